// Round 5
// baseline (218.566 us; speedup 1.0000x reference)
//
#include <hip/hip_runtime.h>

// Heat2D: B=C=H=W=KD=64. All big matmuls via split-bf16 (hi/lo) MFMA,
// LN folded into matmul epilogues where possible.
//   k_pre1: transposed split-bf16 weights (g*Wk)^T, (g*Wz)^T, Wo^T; su/v
//           LN-fold vectors; cos table split bf16.
//   k_pre2: z = LN(freq)@Wz+bz via MFMA (LN folded) -> siluzT/wexpT [c][h][w];
//           freqT[c][h][w] transpose.
//   k_k:    per (b,h): LN_c(x^T+freq)@Wk' (LN folded) -> planes PACKED split
//           u32 (hi<<16|lo), layout [b][n][h][w]. Single barrier; LN stats in
//           FP64 (var = E[x2]-mu2 cancellation was the R4 accuracy failure).
//   k_spec: per (b,c): P2 = C*((C*P*C).*wexp)*C; reads packed planes, writes
//           fp32 in place (k_out needs full precision t).
//   k_out:  per (b,h): ((LN_c(planes)*g_o+b_o)*siluz)@Wo + bo -> out BCHW.
//           LN stats in FP64 (t has large mean/std ratio -> cancellation).

typedef __attribute__((ext_vector_type(8))) short short8;
typedef __attribute__((ext_vector_type(4))) float f32x4;
typedef __attribute__((ext_vector_type(4))) unsigned short us4;

__device__ __forceinline__ unsigned short bfhi(float f) {
    return (unsigned short)(__builtin_bit_cast(unsigned int, f) >> 16);
}
__device__ __forceinline__ float hif(float f) {
    return __builtin_bit_cast(float, __builtin_bit_cast(unsigned int, f) & 0xFFFF0000u);
}
__device__ __forceinline__ unsigned int packsplit(float f) {
    unsigned int h = (unsigned int)bfhi(f);
    unsigned int l = (unsigned int)bfhi(f - hif(f));
    return (h << 16) | l;
}
// swizzled byte address in 64x64 bf16 row-major buffer (128B rows, 16B chunks
// XOR'd with row&7): bank-uniform for b128 frag reads and b64/u16 writes.
__device__ __forceinline__ int swa(int row, int col) {
    return (row << 7) + (((col >> 3) ^ (row & 7)) << 4) + ((col & 7) << 1);
}
__device__ __forceinline__ short8 fragrd(const short* buf, int row, int kc) {
    int a = (row << 7) + ((kc ^ (row & 7)) << 4);
    return *(const short8*)((const char*)buf + a);
}

// 64x64x64 matmul, 4 waves: wave computes 32x32 quadrant (2x2 16x16 tiles).
// D[m][n] = sum_k A[m][k]*B^T[n][k], 3-term split-bf16 (hh + hl + lh).
__device__ __forceinline__ void mm_block(const short* Ah, const short* Al,
                                         const short* Bh, const short* Bl,
                                         int m0, int n0, int l15, int q,
                                         f32x4 (&acc)[2][2]) {
    const f32x4 zero = {0.f, 0.f, 0.f, 0.f};
    acc[0][0] = zero; acc[0][1] = zero; acc[1][0] = zero; acc[1][1] = zero;
    #pragma unroll
    for (int kb = 0; kb < 2; ++kb) {
        int kc = (kb << 2) + q;
        short8 a0h = fragrd(Ah, m0 + l15, kc);
        short8 a0l = fragrd(Al, m0 + l15, kc);
        short8 a1h = fragrd(Ah, m0 + 16 + l15, kc);
        short8 a1l = fragrd(Al, m0 + 16 + l15, kc);
        short8 b0h = fragrd(Bh, n0 + l15, kc);
        short8 b0l = fragrd(Bl, n0 + l15, kc);
        short8 b1h = fragrd(Bh, n0 + 16 + l15, kc);
        short8 b1l = fragrd(Bl, n0 + 16 + l15, kc);
        acc[0][0] = __builtin_amdgcn_mfma_f32_16x16x32_bf16(a0h, b0h, acc[0][0], 0, 0, 0);
        acc[0][0] = __builtin_amdgcn_mfma_f32_16x16x32_bf16(a0h, b0l, acc[0][0], 0, 0, 0);
        acc[0][0] = __builtin_amdgcn_mfma_f32_16x16x32_bf16(a0l, b0h, acc[0][0], 0, 0, 0);
        acc[0][1] = __builtin_amdgcn_mfma_f32_16x16x32_bf16(a0h, b1h, acc[0][1], 0, 0, 0);
        acc[0][1] = __builtin_amdgcn_mfma_f32_16x16x32_bf16(a0h, b1l, acc[0][1], 0, 0, 0);
        acc[0][1] = __builtin_amdgcn_mfma_f32_16x16x32_bf16(a0l, b1h, acc[0][1], 0, 0, 0);
        acc[1][0] = __builtin_amdgcn_mfma_f32_16x16x32_bf16(a1h, b0h, acc[1][0], 0, 0, 0);
        acc[1][0] = __builtin_amdgcn_mfma_f32_16x16x32_bf16(a1h, b0l, acc[1][0], 0, 0, 0);
        acc[1][0] = __builtin_amdgcn_mfma_f32_16x16x32_bf16(a1l, b0h, acc[1][0], 0, 0, 0);
        acc[1][1] = __builtin_amdgcn_mfma_f32_16x16x32_bf16(a1h, b1h, acc[1][1], 0, 0, 0);
        acc[1][1] = __builtin_amdgcn_mfma_f32_16x16x32_bf16(a1h, b1l, acc[1][1], 0, 0, 0);
        acc[1][1] = __builtin_amdgcn_mfma_f32_16x16x32_bf16(a1l, b1h, acc[1][1], 0, 0, 0);
    }
}

// ---------------- k_pre1 ----------------
__global__ __launch_bounds__(256) void k_pre1(
    const float* __restrict__ g_k, const float* __restrict__ b_k,
    const float* __restrict__ Wk, const float* __restrict__ bk,
    const float* __restrict__ g_z, const float* __restrict__ b_z,
    const float* __restrict__ Wz, const float* __restrict__ bz,
    const float* __restrict__ Wo,
    unsigned short* __restrict__ WkTh, unsigned short* __restrict__ WkTl,
    float* __restrict__ su_k, float* __restrict__ v_k,
    unsigned short* __restrict__ WzTh, unsigned short* __restrict__ WzTl,
    float* __restrict__ su_z, float* __restrict__ v_z,
    unsigned short* __restrict__ WoTh, unsigned short* __restrict__ WoTl,
    unsigned short* __restrict__ cos_hi, unsigned short* __restrict__ cos_lo) {
    int t = threadIdx.x;
    if (blockIdx.x < 16) {
        int n = blockIdx.x * 4 + (t >> 6);
        int c = t & 63;
        float wk = Wk[c * 64 + n];
        float a = g_k[c] * wk;
        WkTh[n * 64 + c] = bfhi(a);
        WkTl[n * 64 + c] = bfhi(a - hif(a));
        float sa = a, sv = b_k[c] * wk;
        #pragma unroll
        for (int off = 32; off > 0; off >>= 1) {
            sa += __shfl_xor(sa, off, 64);
            sv += __shfl_xor(sv, off, 64);
        }
        if (c == 0) { su_k[n] = sa; v_k[n] = sv + bk[n]; }
        float wz = Wz[c * 64 + n];
        float az = g_z[c] * wz;
        WzTh[n * 64 + c] = bfhi(az);
        WzTl[n * 64 + c] = bfhi(az - hif(az));
        float saz = az, svz = b_z[c] * wz;
        #pragma unroll
        for (int off = 32; off > 0; off >>= 1) {
            saz += __shfl_xor(saz, off, 64);
            svz += __shfl_xor(svz, off, 64);
        }
        if (c == 0) { su_z[n] = saz; v_z[n] = svz + bz[n]; }
        float wo = Wo[c * 64 + n];
        WoTh[n * 64 + c] = bfhi(wo);
        WoTl[n * 64 + c] = bfhi(wo - hif(wo));
    } else {
        int idx = (blockIdx.x - 16) * 256 + t;
        int i = idx >> 6, j = idx & 63;
        float ang = (float)(i * j) * 3.14159265358979323846f * (1.0f / 64.0f);
        float v = cosf(ang) * (1.0f / 64.0f);
        cos_hi[idx] = bfhi(v);
        cos_lo[idx] = bfhi(v - hif(v));
    }
}

// ---------------- k_pre2: z via MFMA (LN folded) + freq transpose ----------------
__global__ __launch_bounds__(256) void k_pre2(
    const float* __restrict__ freq,
    const unsigned short* __restrict__ WzTh_g, const unsigned short* __restrict__ WzTl_g,
    const float* __restrict__ su_z, const float* __restrict__ v_z,
    float* __restrict__ siluzT, float* __restrict__ wexpT,
    float* __restrict__ freqT) {
    __shared__ short Ah[4096], Al[4096], Bh[4096], Bl[4096];
    __shared__ float muS[64], rsS[64];
    __shared__ float tile[64][65];
    int t = threadIdx.x;
    if (blockIdx.x < 64) {
        int h = blockIdx.x;
        #pragma unroll
        for (int p = 0; p < 2; ++p) {
            int e = t + p * 256;
            int row = e >> 3, ch = e & 7;
            int a = (row << 7) + (((ch ^ (row & 7)) << 4));
            *(uint4*)((char*)Bh + a) = *(const uint4*)&WzTh_g[row * 64 + ch * 8];
            *(uint4*)((char*)Bl + a) = *(const uint4*)&WzTl_g[row * 64 + ch * 8];
        }
        int w = t >> 2, c0 = (t & 3) << 4;
        float4 fr[4];
        double s1 = 0.0, s2 = 0.0;
        #pragma unroll
        for (int i = 0; i < 4; ++i) {
            fr[i] = *(const float4*)&freq[(h * 64 + w) * 64 + c0 + 4 * i];
            const float* fp = (const float*)&fr[i];
            #pragma unroll
            for (int r = 0; r < 4; ++r) {
                double d = (double)fp[r];
                s1 += d; s2 += d * d;
            }
        }
        s1 += __shfl_xor(s1, 1, 64); s1 += __shfl_xor(s1, 2, 64);
        s2 += __shfl_xor(s2, 1, 64); s2 += __shfl_xor(s2, 2, 64);
        double mu = s1 * (1.0 / 64.0);
        double var = s2 * (1.0 / 64.0) - mu * mu;
        float rs = rsqrtf((float)(var + 1e-5));
        if ((t & 3) == 0) { muS[w] = (float)mu; rsS[w] = rs; }
        const float* fp = (const float*)fr;
        #pragma unroll
        for (int i = 0; i < 4; ++i) {
            us4 hv, lv;
            #pragma unroll
            for (int r = 0; r < 4; ++r) {
                float f = fp[i * 4 + r];
                hv[r] = bfhi(f);
                lv[r] = bfhi(f - hif(f));
            }
            int a = swa(w, c0 + 4 * i);
            *(us4*)((char*)Ah + a) = hv;
            *(us4*)((char*)Al + a) = lv;
        }
        __syncthreads();
        int lane = t & 63, wv = t >> 6;
        int q = lane >> 4, l15 = lane & 15;
        int m0 = (wv & 1) << 5, n0 = (wv >> 1) << 5;
        f32x4 acc[2][2];
        mm_block(Ah, Al, Bh, Bl, m0, n0, l15, q, acc);
        #pragma unroll
        for (int u = 0; u < 2; ++u) {
            int c = n0 + (u << 4) + l15;
            float suc = su_z[c], vc = v_z[c];
            #pragma unroll
            for (int ti = 0; ti < 2; ++ti) {
                int wb = m0 + (ti << 4) + (q << 2);
                float4 mu4 = *(const float4*)&muS[wb];
                float4 rs4 = *(const float4*)&rsS[wb];
                float4 sil, wx;
                #pragma unroll
                for (int r = 0; r < 4; ++r) {
                    float z = ((const float*)&rs4)[r] * (acc[ti][u][r] - ((const float*)&mu4)[r] * suc) + vc;
                    float lnd = -(float)(h + wb + r) * 0.015625f - 4.1588830833596718565f;
                    ((float*)&sil)[r] = z / (1.0f + expf(-z));
                    ((float*)&wx)[r] = expf(z * lnd);
                }
                int base = (c * 64 + h) * 64 + wb;
                *(float4*)&siluzT[base] = sil;
                *(float4*)&wexpT[base] = wx;
            }
        }
    } else {
        int h = blockIdx.x - 64;
        int w = t >> 2, c0 = (t & 3) << 4;
        #pragma unroll
        for (int i = 0; i < 4; ++i)
            *(float4*)&tile[w][c0 + 4 * i] = *(const float4*)&freq[(h * 64 + w) * 64 + c0 + 4 * i];
        __syncthreads();
        int w0 = (t & 15) << 2;
        #pragma unroll
        for (int p = 0; p < 4; ++p) {
            int c = (t >> 4) + 16 * p;
            float4 fv = make_float4(tile[w0][c], tile[w0 + 1][c], tile[w0 + 2][c], tile[w0 + 3][c]);
            *(float4*)&freqT[(c * 64 + h) * 64 + w0] = fv;
        }
    }
}

// ---------------- k_k: single-barrier, FP64 LN stats, packed-split output ----------------
__global__ __launch_bounds__(256, 4) void k_k(
    const float* __restrict__ x, const float* __restrict__ freqT,
    const unsigned short* __restrict__ WkTh_g, const unsigned short* __restrict__ WkTl_g,
    const float* __restrict__ su_k, const float* __restrict__ v_k,
    unsigned int* __restrict__ planes) {
    __shared__ short Ah[4096], Al[4096], Bh[4096], Bl[4096];
    __shared__ double red1[4][64], red2[4][64];
    int b = blockIdx.x >> 6, h = blockIdx.x & 63;
    int t = threadIdx.x;
    int lane = t & 63, wv = t >> 6;
    int q = lane >> 4, l15 = lane & 15;
    #pragma unroll
    for (int p = 0; p < 2; ++p) {
        int e = t + p * 256;
        int row = e >> 3, ch = e & 7;
        int a = (row << 7) + (((ch ^ (row & 7)) << 4));
        *(uint4*)((char*)Bh + a) = *(const uint4*)&WkTh_g[row * 64 + ch * 8];
        *(uint4*)((char*)Bl + a) = *(const uint4*)&WkTl_g[row * 64 + ch * 8];
    }
    // load xin = x + freqT; thread: 4c x 4w block
    int g = t >> 4, w0 = (t & 15) << 2, c0 = g << 2;
    const float* xb = x + (size_t)b * 262144 + h * 64;
    float4 vr[4];
    double s1[4] = {0,0,0,0}, s2[4] = {0,0,0,0};
    #pragma unroll
    for (int i = 0; i < 4; ++i) {
        int c = c0 + i;
        float4 xv = *(const float4*)&xb[c * 4096 + w0];
        float4 fv = *(const float4*)&freqT[c * 4096 + h * 64 + w0];
        xv.x += fv.x; xv.y += fv.y; xv.z += fv.z; xv.w += fv.w;
        vr[i] = xv;
        const float* xp = (const float*)&xv;
        #pragma unroll
        for (int r = 0; r < 4; ++r) {
            double d = (double)xp[r];
            s1[r] += d; s2[r] += d * d;
        }
    }
    // in-wave partials over the wave's 16 c's (q-axis)
    #pragma unroll
    for (int off = 16; off <= 32; off <<= 1) {
        #pragma unroll
        for (int r = 0; r < 4; ++r) {
            s1[r] += __shfl_xor(s1[r], off, 64);
            s2[r] += __shfl_xor(s2[r], off, 64);
        }
    }
    if (q == 0) {
        #pragma unroll
        for (int r = 0; r < 4; ++r) {
            red1[wv][(l15 << 2) + r] = s1[r];
            red2[wv][(l15 << 2) + r] = s2[r];
        }
    }
    // split + transpose-write A = xinT[w][c]
    const float* vp = (const float*)vr;
    #pragma unroll
    for (int j = 0; j < 4; ++j) {
        us4 hv, lv;
        #pragma unroll
        for (int r = 0; r < 4; ++r) {
            float f = vp[r * 4 + j];
            hv[r] = bfhi(f);
            lv[r] = bfhi(f - hif(f));
        }
        int a = swa(w0 + j, c0);
        *(us4*)((char*)Ah + a) = hv;
        *(us4*)((char*)Al + a) = lv;
    }
    __syncthreads();   // the only barrier
    int m0 = (wv & 1) << 5, n0 = (wv >> 1) << 5;
    f32x4 acc[2][2];
    mm_block(Ah, Al, Bh, Bl, m0, n0, l15, q, acc);
    #pragma unroll
    for (int ti = 0; ti < 2; ++ti) {
        int wb = m0 + (ti << 4) + (q << 2);
        float4 mu4, rs4;
        #pragma unroll
        for (int r = 0; r < 4; ++r) {
            double a1 = red1[0][wb + r] + red1[1][wb + r] + red1[2][wb + r] + red1[3][wb + r];
            double a2 = red2[0][wb + r] + red2[1][wb + r] + red2[2][wb + r] + red2[3][wb + r];
            double mu = a1 * (1.0 / 64.0);
            double var = a2 * (1.0 / 64.0) - mu * mu;
            ((float*)&mu4)[r] = (float)mu;
            ((float*)&rs4)[r] = rsqrtf((float)(var + 1e-5));
        }
        #pragma unroll
        for (int u = 0; u < 2; ++u) {
            int n = n0 + (u << 4) + l15;
            float sun = su_k[n], vn = v_k[n];
            uint4 o;
            o.x = packsplit(rs4.x * (acc[ti][u][0] - mu4.x * sun) + vn);
            o.y = packsplit(rs4.y * (acc[ti][u][1] - mu4.y * sun) + vn);
            o.z = packsplit(rs4.z * (acc[ti][u][2] - mu4.z * sun) + vn);
            o.w = packsplit(rs4.w * (acc[ti][u][3] - mu4.w * sun) + vn);
            *(uint4*)&planes[((size_t)(b * 64 + n) * 64 + h) * 64 + wb] = o;
        }
    }
}

// ---------------- k_spec: reads packed split planes, writes fp32 in place ----------------
__global__ __launch_bounds__(256, 3) void k_spec(
    unsigned int* __restrict__ planes,
    const unsigned short* __restrict__ cos_hi, const unsigned short* __restrict__ cos_lo,
    const float* __restrict__ wexpT) {
    __shared__ short Ch[4096], Cl[4096];
    __shared__ short D0h[4096], D0l[4096];
    __shared__ short D1h[4096], D1l[4096];
    int b = blockIdx.x >> 6, c = blockIdx.x & 63;
    unsigned int* pu = planes + (size_t)(b * 64 + c) * 4096;
    float* po = (float*)pu;
    int t = threadIdx.x;
    int lane = t & 63, wv = t >> 6;
    int q = lane >> 4, l15 = lane & 15;
    int m0 = (wv & 1) << 5, n0 = (wv >> 1) << 5;

    {
        int r = t >> 2, cb = (t & 3) << 4;
        #pragma unroll
        for (int p = 0; p < 2; ++p) {
            int chunk = (cb >> 3) + p;
            int a = (r << 7) + (((chunk ^ (r & 7)) << 4));
            *(uint4*)((char*)Ch + a) = *(const uint4*)&cos_hi[r * 64 + cb + p * 8];
            *(uint4*)((char*)Cl + a) = *(const uint4*)&cos_lo[r * 64 + cb + p * 8];
        }
    }
    // stage P^T into D0 (rows = w): unpack packed split u32
    {
        int w = t & 63, h0 = (t >> 6) << 4;
        unsigned int v[16];
        #pragma unroll
        for (int j = 0; j < 16; ++j) v[j] = pu[(h0 + j) * 64 + w];
        #pragma unroll
        for (int g = 0; g < 4; ++g) {
            int col = h0 + (g << 2);
            int a = swa(w, col);
            us4 hv, lv;
            #pragma unroll
            for (int r = 0; r < 4; ++r) {
                unsigned int pv = v[(g << 2) + r];
                hv[r] = (unsigned short)(pv >> 16);
                lv[r] = (unsigned short)(pv & 0xFFFFu);
            }
            *(us4*)((char*)D0h + a) = hv;
            *(us4*)((char*)D0l + a) = lv;
        }
    }
    __syncthreads();

    f32x4 acc[2][2];

#define WB_T(Dh, Dl)                                                                \
    {                                                                               \
        _Pragma("unroll")                                                           \
        for (int ti = 0; ti < 2; ++ti)                                              \
            _Pragma("unroll")                                                       \
            for (int u = 0; u < 2; ++u) {                                           \
                int row = n0 + (u << 4) + l15;                                      \
                int col = m0 + (ti << 4) + (q << 2);                                \
                int a = swa(row, col);                                              \
                us4 hv, lv;                                                         \
                _Pragma("unroll")                                                   \
                for (int r = 0; r < 4; ++r) {                                       \
                    float f = acc[ti][u][r];                                        \
                    hv[r] = bfhi(f);                                                \
                    lv[r] = bfhi(f - hif(f));                                       \
                }                                                                   \
                *(us4*)((char*)Dh + a) = hv;                                        \
                *(us4*)((char*)Dl + a) = lv;                                        \
            }                                                                       \
    }

    // M1
    mm_block(D0h, D0l, Ch, Cl, m0, n0, l15, q, acc);
    WB_T(D1h, D1l)
    __syncthreads();
    // M2 + gate
    mm_block(D1h, D1l, Ch, Cl, m0, n0, l15, q, acc);
    {
        const float* wx = wexpT + (size_t)c * 4096;
        #pragma unroll
        for (int ti = 0; ti < 2; ++ti)
            #pragma unroll
            for (int u = 0; u < 2; ++u)
                #pragma unroll
                for (int r = 0; r < 4; ++r) {
                    int n = m0 + (ti << 4) + (q << 2) + r;
                    int m = n0 + (u << 4) + l15;
                    acc[ti][u][r] *= wx[n * 64 + m];
                }
    }
    WB_T(D0h, D0l)
    __syncthreads();
    // M3 (row-major WB via u16 scatter)
    mm_block(Ch, Cl, D0h, D0l, m0, n0, l15, q, acc);
    {
        #pragma unroll
        for (int ti = 0; ti < 2; ++ti)
            #pragma unroll
            for (int u = 0; u < 2; ++u)
                #pragma unroll
                for (int r = 0; r < 4; ++r) {
                    int row = m0 + (ti << 4) + (q << 2) + r;
                    int col = n0 + (u << 4) + l15;
                    int a = swa(row, col);
                    float f = acc[ti][u][r];
                    *(unsigned short*)((char*)D1h + a) = bfhi(f);
                    *(unsigned short*)((char*)D1l + a) = bfhi(f - hif(f));
                }
    }
    __syncthreads();
    // M4 -> global fp32 in place
    mm_block(D1h, D1l, Ch, Cl, m0, n0, l15, q, acc);
    {
        #pragma unroll
        for (int ti = 0; ti < 2; ++ti)
            #pragma unroll
            for (int u = 0; u < 2; ++u)
                #pragma unroll
                for (int r = 0; r < 4; ++r) {
                    int h = m0 + (ti << 4) + (q << 2) + r;
                    int w = n0 + (u << 4) + l15;
                    po[h * 64 + w] = acc[ti][u][r];
                }
    }
#undef WB_T
}

// ---------------- k_out: FP64 LN stats (2 barriers) ----------------
__global__ __launch_bounds__(256, 4) void k_out(
    const float* __restrict__ planes, const float* __restrict__ siluzT,
    const float* __restrict__ g_o, const float* __restrict__ b_o,
    const unsigned short* __restrict__ WoTh_g, const unsigned short* __restrict__ WoTl_g,
    const float* __restrict__ bo, float* __restrict__ out) {
    __shared__ short Ah[4096], Al[4096], Bh[4096], Bl[4096];
    __shared__ double red1[4][64], red2[4][64];
    int b = blockIdx.x >> 6, h = blockIdx.x & 63;
    int t = threadIdx.x;
    int lane = t & 63, wv = t >> 6;
    int q = lane >> 4, l15 = lane & 15;
    #pragma unroll
    for (int p = 0; p < 2; ++p) {
        int e = t + p * 256;
        int row = e >> 3, ch = e & 7;
        int a = (row << 7) + (((ch ^ (row & 7)) << 4));
        *(uint4*)((char*)Bh + a) = *(const uint4*)&WoTh_g[row * 64 + ch * 8];
        *(uint4*)((char*)Bl + a) = *(const uint4*)&WoTl_g[row * 64 + ch * 8];
    }
    int g = t >> 4, w0 = (t & 15) << 2, c0 = g << 2;
    const float* pb = planes + (size_t)b * 262144 + h * 64;
    float4 vr[4], szr[4];
    double s1[4] = {0,0,0,0}, s2[4] = {0,0,0,0};
    #pragma unroll
    for (int i = 0; i < 4; ++i) {
        int c = c0 + i;
        float4 tv = *(const float4*)&pb[c * 4096 + w0];
        szr[i] = *(const float4*)&siluzT[c * 4096 + h * 64 + w0];
        vr[i] = tv;
        const float* xp = (const float*)&tv;
        #pragma unroll
        for (int r = 0; r < 4; ++r) {
            double d = (double)xp[r];
            s1[r] += d; s2[r] += d * d;
        }
    }
    #pragma unroll
    for (int off = 16; off <= 32; off <<= 1) {
        #pragma unroll
        for (int r = 0; r < 4; ++r) {
            s1[r] += __shfl_xor(s1[r], off, 64);
            s2[r] += __shfl_xor(s2[r], off, 64);
        }
    }
    if (q == 0) {
        #pragma unroll
        for (int r = 0; r < 4; ++r) {
            red1[wv][(l15 << 2) + r] = s1[r];
            red2[wv][(l15 << 2) + r] = s2[r];
        }
    }
    __syncthreads();   // barrier 1: red ready
    // stats for this thread's own w0-quad
    {
        float4 mu4, rs4;
        #pragma unroll
        for (int r = 0; r < 4; ++r) {
            double a1 = red1[0][w0 + r] + red1[1][w0 + r] + red1[2][w0 + r] + red1[3][w0 + r];
            double a2 = red2[0][w0 + r] + red2[1][w0 + r] + red2[2][w0 + r] + red2[3][w0 + r];
            double mu = a1 * (1.0 / 64.0);
            double var = a2 * (1.0 / 64.0) - mu * mu;
            ((float*)&mu4)[r] = (float)mu;
            ((float*)&rs4)[r] = rsqrtf((float)(var + 1e-5));
        }
        #pragma unroll
        for (int i = 0; i < 4; ++i) {
            int c = c0 + i;
            float go = g_o[c], boc = b_o[c];
            vr[i].x = ((vr[i].x - mu4.x) * rs4.x * go + boc) * szr[i].x;
            vr[i].y = ((vr[i].y - mu4.y) * rs4.y * go + boc) * szr[i].y;
            vr[i].z = ((vr[i].z - mu4.z) * rs4.z * go + boc) * szr[i].z;
            vr[i].w = ((vr[i].w - mu4.w) * rs4.w * go + boc) * szr[i].w;
        }
        const float* vp = (const float*)vr;
        #pragma unroll
        for (int j = 0; j < 4; ++j) {
            us4 hv, lv;
            #pragma unroll
            for (int r = 0; r < 4; ++r) {
                float f = vp[r * 4 + j];
                hv[r] = bfhi(f);
                lv[r] = bfhi(f - hif(f));
            }
            int a = swa(w0 + j, c0);
            *(us4*)((char*)Ah + a) = hv;
            *(us4*)((char*)Al + a) = lv;
        }
    }
    __syncthreads();   // barrier 2: A ready
    int m0 = (wv & 1) << 5, n0 = (wv >> 1) << 5;
    f32x4 acc[2][2];
    mm_block(Ah, Al, Bh, Bl, m0, n0, l15, q, acc);
    #pragma unroll
    for (int u = 0; u < 2; ++u) {
        int o_ = n0 + (u << 4) + l15;
        float bov = bo[o_];
        #pragma unroll
        for (int ti = 0; ti < 2; ++ti) {
            int wb = m0 + (ti << 4) + (q << 2);
            float4 o;
            o.x = acc[ti][u][0] + bov;
            o.y = acc[ti][u][1] + bov;
            o.z = acc[ti][u][2] + bov;
            o.w = acc[ti][u][3] + bov;
            *(float4*)&out[((size_t)(b * 64 + o_) * 64 + h) * 64 + wb] = o;
        }
    }
}

extern "C" void kernel_launch(void* const* d_in, const int* in_sizes, int n_in,
                              void* d_out, int out_size, void* d_ws, size_t ws_size,
                              hipStream_t stream) {
    const float* x    = (const float*)d_in[0];
    const float* freq = (const float*)d_in[1];
    const float* g_k  = (const float*)d_in[2];
    const float* b_k  = (const float*)d_in[3];
    const float* Wk   = (const float*)d_in[4];
    const float* bk   = (const float*)d_in[5];
    const float* g_z  = (const float*)d_in[6];
    const float* b_z  = (const float*)d_in[7];
    const float* Wz   = (const float*)d_in[8];
    const float* bz   = (const float*)d_in[9];
    const float* g_o  = (const float*)d_in[10];
    const float* b_o  = (const float*)d_in[11];
    const float* Wo   = (const float*)d_in[12];
    const float* bo   = (const float*)d_in[13];
    float* out = (float*)d_out;

    float* ws = (float*)d_ws;
    float* planes = ws;                                   // 16777216 f (packed u32 then fp32)
    float* siluzT = planes + 16777216;                    // 262144 f
    float* wexpT  = siluzT + 262144;                      // 262144 f
    float* freqT  = wexpT + 262144;                       // 262144 f
    float* su_k   = freqT + 262144;                       // 64
    float* v_k    = su_k + 64;
    float* su_z   = v_k + 64;
    float* v_z    = su_z + 64;
    unsigned short* cos_hi = (unsigned short*)(v_z + 64); // 4096 u16 each
    unsigned short* cos_lo = cos_hi + 4096;
    unsigned short* WkTh = cos_lo + 4096;
    unsigned short* WkTl = WkTh + 4096;
    unsigned short* WzTh = WkTl + 4096;
    unsigned short* WzTl = WzTh + 4096;
    unsigned short* WoTh = WzTl + 4096;
    unsigned short* WoTl = WoTh + 4096;

    k_pre1<<<32, 256, 0, stream>>>(g_k, b_k, Wk, bk, g_z, b_z, Wz, bz, Wo,
                                   WkTh, WkTl, su_k, v_k, WzTh, WzTl, su_z, v_z,
                                   WoTh, WoTl, cos_hi, cos_lo);
    k_pre2<<<128, 256, 0, stream>>>(freq, WzTh, WzTl, su_z, v_z, siluzT, wexpT, freqT);
    k_k<<<4096, 256, 0, stream>>>(x, freqT, WkTh, WkTl, su_k, v_k, (unsigned int*)planes);
    k_spec<<<4096, 256, 0, stream>>>((unsigned int*)planes, cos_hi, cos_lo, wexpT);
    k_out<<<4096, 256, 0, stream>>>(planes, siluzT, g_o, b_o, WoTh, WoTl, bo, out);
}